// Round 1
// baseline (1189.865 us; speedup 1.0000x reference)
//
#include <hip/hip_runtime.h>

#define N_NODES 40000
#define N_EDGES 640000
#define D_FEAT  128

// One edge handled by 32 threads (half-wave): lane l covers features [4l, 4l+4).
// x row gather is a coalesced float4 load (512 B per edge across 32 lanes).
__global__ __launch_bounds__(256) void edge_scatter_kernel(
    const float* __restrict__ x,
    const int*   __restrict__ rows,
    const int*   __restrict__ cols,
    const float* __restrict__ vals,
    float*       __restrict__ agg,   // d_out, pre-zeroed
    float*       __restrict__ deg)   // d_ws, pre-zeroed
{
    int t    = blockIdx.x * blockDim.x + threadIdx.x;
    int edge = t >> 5;
    if (edge >= N_EDGES) return;
    int lane = t & 31;

    int   row = rows[edge];
    int   col = cols[edge];
    float v   = vals[edge];

    const float4* xr = (const float4*)(x + (size_t)col * D_FEAT);
    float4 xv = xr[lane];

    float* dst = agg + (size_t)row * D_FEAT + lane * 4;
    unsafeAtomicAdd(dst + 0, v * xv.x);
    unsafeAtomicAdd(dst + 1, v * xv.y);
    unsafeAtomicAdd(dst + 2, v * xv.z);
    unsafeAtomicAdd(dst + 3, v * xv.w);

    if (lane == 0) unsafeAtomicAdd(deg + row, v);
}

// out[n][d] = (deg[n]==0 ? 0 : agg[n][d]/deg[n]) + bias[d]
__global__ __launch_bounds__(256) void finalize_kernel(
    float*       __restrict__ out,
    const float* __restrict__ deg,
    const float* __restrict__ bias)
{
    int t    = blockIdx.x * blockDim.x + threadIdx.x;
    int node = t >> 5;
    if (node >= N_NODES) return;
    int lane = t & 31;

    float d   = deg[node];
    float inv = (d == 0.0f) ? 0.0f : 1.0f / d;

    float4*       o = (float4*)(out + (size_t)node * D_FEAT) + lane;
    const float4* b = (const float4*)bias + lane;
    float4 ov = *o;
    float4 bv = *b;
    ov.x = ov.x * inv + bv.x;
    ov.y = ov.y * inv + bv.y;
    ov.z = ov.z * inv + bv.z;
    ov.w = ov.w * inv + bv.w;
    *o = ov;
}

extern "C" void kernel_launch(void* const* d_in, const int* in_sizes, int n_in,
                              void* d_out, int out_size, void* d_ws, size_t ws_size,
                              hipStream_t stream) {
    const float* x    = (const float*)d_in[0];
    const int*   rows = (const int*)  d_in[1];
    const int*   cols = (const int*)  d_in[2];
    const float* vals = (const float*)d_in[3];
    const float* bias = (const float*)d_in[4];

    float* out = (float*)d_out;
    float* deg = (float*)d_ws;   // N_NODES floats of scratch

    // Zero accumulators (workspace/out are poisoned 0xAA before every call).
    hipMemsetAsync(out, 0, (size_t)N_NODES * D_FEAT * sizeof(float), stream);
    hipMemsetAsync(deg, 0, (size_t)N_NODES * sizeof(float), stream);

    {
        int threads = N_EDGES * 32;
        dim3 grid((threads + 255) / 256), block(256);
        edge_scatter_kernel<<<grid, block, 0, stream>>>(x, rows, cols, vals, out, deg);
    }
    {
        int threads = N_NODES * 32;
        dim3 grid((threads + 255) / 256), block(256);
        finalize_kernel<<<grid, block, 0, stream>>>(out, deg, bias);
    }
}

// Round 2
// 268.581 us; speedup vs baseline: 4.4302x; 4.4302x over previous
//
#include <hip/hip_runtime.h>

#define N_NODES 40000
#define N_EDGES 640000
#define D_FEAT  128
#define SCAN_THREADS 1024

// ---------------- CSR build ----------------

__global__ __launch_bounds__(256) void histogram_kernel(
    const int* __restrict__ rows, int* __restrict__ counts)
{
    int e = blockIdx.x * blockDim.x + threadIdx.x;
    if (e < N_EDGES) atomicAdd(&counts[rows[e]], 1);
}

// Single-workgroup exclusive scan over 40000 counts -> offsets, cursors.
__global__ __launch_bounds__(SCAN_THREADS) void scan_kernel(
    const int* __restrict__ counts,
    int* __restrict__ offsets,
    int* __restrict__ cursors)
{
    __shared__ int partials[SCAN_THREADS];
    int t = threadIdx.x;
    const int chunk = (N_NODES + SCAN_THREADS - 1) / SCAN_THREADS;  // 40
    int beg = t * chunk;
    int end = min(beg + chunk, N_NODES);

    int sum = 0;
    for (int i = beg; i < end; ++i) sum += counts[i];
    partials[t] = sum;
    __syncthreads();

    // Hillis-Steele inclusive scan in LDS
    for (int off = 1; off < SCAN_THREADS; off <<= 1) {
        int v = (t >= off) ? partials[t - off] : 0;
        __syncthreads();
        if (t >= off) partials[t] += v;
        __syncthreads();
    }
    int run = (t == 0) ? 0 : partials[t - 1];  // exclusive prefix of my chunk

    for (int i = beg; i < end; ++i) {
        offsets[i] = run;
        cursors[i] = run;
        run += counts[i];
    }
    if (t == SCAN_THREADS - 1) offsets[N_NODES] = run;
}

// bucket[pos] = {col, val} grouped by row
__global__ __launch_bounds__(256) void bucket_kernel(
    const int*   __restrict__ rows,
    const int*   __restrict__ cols,
    const float* __restrict__ vals,
    int*         __restrict__ cursors,
    int2*        __restrict__ bucket)
{
    int e = blockIdx.x * blockDim.x + threadIdx.x;
    if (e >= N_EDGES) return;
    int r = rows[e];
    int pos = atomicAdd(&cursors[r], 1);
    bucket[pos] = make_int2(cols[e], __float_as_int(vals[e]));
}

// ---------------- Gather: one half-wave (32 lanes) per node ----------------

__global__ __launch_bounds__(256) void gather_kernel(
    const float* __restrict__ x,
    const int*   __restrict__ offsets,
    const int2*  __restrict__ bucket,
    const float* __restrict__ bias,
    float*       __restrict__ out)
{
    int t    = blockIdx.x * blockDim.x + threadIdx.x;
    int node = t >> 5;
    if (node >= N_NODES) return;
    int lane = t & 31;

    int beg = offsets[node];
    int end = offsets[node + 1];

    float4 acc = make_float4(0.f, 0.f, 0.f, 0.f);
    float  deg = 0.f;

    for (int e = beg; e < end; ++e) {
        int2  ent = bucket[e];               // uniform addr across half-wave: broadcast
        int   c   = ent.x;
        float v   = __int_as_float(ent.y);
        deg += v;
        float4 xv = ((const float4*)(x + (size_t)c * D_FEAT))[lane];
        acc.x += v * xv.x;
        acc.y += v * xv.y;
        acc.z += v * xv.z;
        acc.w += v * xv.w;
    }

    float inv = (deg == 0.f) ? 0.f : 1.f / deg;
    float4 bv = ((const float4*)bias)[lane];
    float4 ov;
    ov.x = acc.x * inv + bv.x;
    ov.y = acc.y * inv + bv.y;
    ov.z = acc.z * inv + bv.z;
    ov.w = acc.w * inv + bv.w;
    ((float4*)(out + (size_t)node * D_FEAT))[lane] = ov;
}

// ---------------- Fallback (round-0 atomic path) ----------------

__global__ __launch_bounds__(256) void edge_scatter_kernel(
    const float* __restrict__ x, const int* __restrict__ rows,
    const int* __restrict__ cols, const float* __restrict__ vals,
    float* __restrict__ agg, float* __restrict__ deg)
{
    int t = blockIdx.x * blockDim.x + threadIdx.x;
    int edge = t >> 5;
    if (edge >= N_EDGES) return;
    int lane = t & 31;
    int row = rows[edge]; int col = cols[edge]; float v = vals[edge];
    float4 xv = ((const float4*)(x + (size_t)col * D_FEAT))[lane];
    float* dst = agg + (size_t)row * D_FEAT + lane * 4;
    unsafeAtomicAdd(dst + 0, v * xv.x);
    unsafeAtomicAdd(dst + 1, v * xv.y);
    unsafeAtomicAdd(dst + 2, v * xv.z);
    unsafeAtomicAdd(dst + 3, v * xv.w);
    if (lane == 0) unsafeAtomicAdd(deg + row, v);
}

__global__ __launch_bounds__(256) void finalize_kernel(
    float* __restrict__ out, const float* __restrict__ deg,
    const float* __restrict__ bias)
{
    int t = blockIdx.x * blockDim.x + threadIdx.x;
    int node = t >> 5;
    if (node >= N_NODES) return;
    int lane = t & 31;
    float d = deg[node];
    float inv = (d == 0.f) ? 0.f : 1.f / d;
    float4* o = (float4*)(out + (size_t)node * D_FEAT) + lane;
    float4 bv = ((const float4*)bias)[lane];
    float4 ov = *o;
    ov.x = ov.x * inv + bv.x; ov.y = ov.y * inv + bv.y;
    ov.z = ov.z * inv + bv.z; ov.w = ov.w * inv + bv.w;
    *o = ov;
}

// ---------------- launch ----------------

extern "C" void kernel_launch(void* const* d_in, const int* in_sizes, int n_in,
                              void* d_out, int out_size, void* d_ws, size_t ws_size,
                              hipStream_t stream) {
    const float* x    = (const float*)d_in[0];
    const int*   rows = (const int*)  d_in[1];
    const int*   cols = (const int*)  d_in[2];
    const float* vals = (const float*)d_in[3];
    const float* bias = (const float*)d_in[4];
    float* out = (float*)d_out;

    // workspace layout (ints): counts[40000] | offsets[40001] | cursors[40000] | bucket int2[640000]
    int* w = (int*)d_ws;
    int* counts  = w;
    int* offsets = w + 40064;           // aligned gap
    int* cursors = w + 80192;
    int2* bucket = (int2*)(w + 120256); // byte offset 481024, 8B-aligned
    size_t needed = 481024 + (size_t)N_EDGES * sizeof(int2);

    if (ws_size >= needed) {
        hipMemsetAsync(counts, 0, N_NODES * sizeof(int), stream);
        histogram_kernel<<<(N_EDGES + 255) / 256, 256, 0, stream>>>(rows, counts);
        scan_kernel<<<1, SCAN_THREADS, 0, stream>>>(counts, offsets, cursors);
        bucket_kernel<<<(N_EDGES + 255) / 256, 256, 0, stream>>>(rows, cols, vals, cursors, bucket);
        int threads = N_NODES * 32;
        gather_kernel<<<(threads + 255) / 256, 256, 0, stream>>>(x, offsets, bucket, bias, out);
    } else {
        float* deg = (float*)d_ws;
        hipMemsetAsync(out, 0, (size_t)N_NODES * D_FEAT * sizeof(float), stream);
        hipMemsetAsync(deg, 0, (size_t)N_NODES * sizeof(float), stream);
        int et = N_EDGES * 32;
        edge_scatter_kernel<<<(et + 255) / 256, 256, 0, stream>>>(x, rows, cols, vals, out, deg);
        int nt = N_NODES * 32;
        finalize_kernel<<<(nt + 255) / 256, 256, 0, stream>>>(out, deg, bias);
    }
}

// Round 3
// 185.630 us; speedup vs baseline: 6.4099x; 1.4469x over previous
//
#include <hip/hip_runtime.h>

#define N_NODES 40000
#define N_EDGES 640000
#define D_FEAT  128
#define SCAN_BLOCK 256
#define N_SCAN_BLOCKS ((N_NODES + SCAN_BLOCK - 1) / SCAN_BLOCK)   // 157

// ---------------- CSR build ----------------

__global__ __launch_bounds__(256) void histogram_kernel(
    const int* __restrict__ rows, int* __restrict__ counts)
{
    int e = blockIdx.x * blockDim.x + threadIdx.x;
    if (e < N_EDGES) atomicAdd(&counts[rows[e]], 1);
}

// Phase 1: per-block exclusive scan of 256 counts; emit block sums.
__global__ __launch_bounds__(SCAN_BLOCK) void scan1_kernel(
    const int* __restrict__ counts,
    int* __restrict__ offsets,      // exclusive-within-block prefix
    int* __restrict__ blocksums)
{
    __shared__ int tmp[SCAN_BLOCK];
    int t = threadIdx.x;
    int g = blockIdx.x * SCAN_BLOCK + t;
    int v = (g < N_NODES) ? counts[g] : 0;
    tmp[t] = v;
    __syncthreads();
    #pragma unroll
    for (int off = 1; off < SCAN_BLOCK; off <<= 1) {
        int add = (t >= off) ? tmp[t - off] : 0;
        __syncthreads();
        tmp[t] += add;
        __syncthreads();
    }
    if (g < N_NODES) offsets[g] = tmp[t] - v;          // exclusive
    if (t == SCAN_BLOCK - 1) blocksums[blockIdx.x] = tmp[t];
}

// Phase 2: single block scans the 157 block sums (exclusive, in place).
__global__ __launch_bounds__(SCAN_BLOCK) void scan2_kernel(
    int* __restrict__ blocksums)
{
    __shared__ int tmp[SCAN_BLOCK];
    int t = threadIdx.x;
    int v = (t < N_SCAN_BLOCKS) ? blocksums[t] : 0;
    tmp[t] = v;
    __syncthreads();
    #pragma unroll
    for (int off = 1; off < SCAN_BLOCK; off <<= 1) {
        int add = (t >= off) ? tmp[t - off] : 0;
        __syncthreads();
        tmp[t] += add;
        __syncthreads();
    }
    if (t < N_SCAN_BLOCKS) blocksums[t] = tmp[t] - v;  // exclusive
}

// Phase 3: add block prefix; init cursors; close the offsets array.
__global__ __launch_bounds__(SCAN_BLOCK) void scan3_kernel(
    int* __restrict__ offsets,
    int* __restrict__ cursors,
    const int* __restrict__ blocksums)
{
    int t = threadIdx.x;
    int g = blockIdx.x * SCAN_BLOCK + t;
    if (g < N_NODES) {
        int o = offsets[g] + blocksums[blockIdx.x];
        offsets[g] = o;
        cursors[g] = o;
    }
    if (g == 0) offsets[N_NODES] = N_EDGES;   // total is statically known
}

// bucket[pos] = {col, val} grouped by row
__global__ __launch_bounds__(256) void bucket_kernel(
    const int*   __restrict__ rows,
    const int*   __restrict__ cols,
    const float* __restrict__ vals,
    int*         __restrict__ cursors,
    int2*        __restrict__ bucket)
{
    int e = blockIdx.x * blockDim.x + threadIdx.x;
    if (e >= N_EDGES) return;
    int r = rows[e];
    int pos = atomicAdd(&cursors[r], 1);
    bucket[pos] = make_int2(cols[e], __float_as_int(vals[e]));
}

// ---------------- Gather: one half-wave (32 lanes) per node ----------------

__global__ __launch_bounds__(256) void gather_kernel(
    const float* __restrict__ x,
    const int*   __restrict__ offsets,
    const int2*  __restrict__ bucket,
    const float* __restrict__ bias,
    float*       __restrict__ out)
{
    int t    = blockIdx.x * blockDim.x + threadIdx.x;
    int node = t >> 5;
    if (node >= N_NODES) return;
    int lane = t & 31;

    int beg = offsets[node];
    int end = offsets[node + 1];

    float4 acc = make_float4(0.f, 0.f, 0.f, 0.f);
    float  deg = 0.f;

    // software-pipelined: prefetch next bucket entry while gathering current x row
    int2 ent = (beg < end) ? bucket[beg] : make_int2(0, 0);
    for (int e = beg; e < end; ++e) {
        int2 cur = ent;
        if (e + 1 < end) ent = bucket[e + 1];
        int   c = cur.x;
        float v = __int_as_float(cur.y);
        deg += v;
        float4 xv = ((const float4*)(x + (size_t)c * D_FEAT))[lane];
        acc.x += v * xv.x;
        acc.y += v * xv.y;
        acc.z += v * xv.z;
        acc.w += v * xv.w;
    }

    float inv = (deg == 0.f) ? 0.f : 1.f / deg;
    float4 bv = ((const float4*)bias)[lane];
    float4 ov;
    ov.x = acc.x * inv + bv.x;
    ov.y = acc.y * inv + bv.y;
    ov.z = acc.z * inv + bv.z;
    ov.w = acc.w * inv + bv.w;
    ((float4*)(out + (size_t)node * D_FEAT))[lane] = ov;
}

// ---------------- Fallback (atomic path, if ws too small) ----------------

__global__ __launch_bounds__(256) void edge_scatter_kernel(
    const float* __restrict__ x, const int* __restrict__ rows,
    const int* __restrict__ cols, const float* __restrict__ vals,
    float* __restrict__ agg, float* __restrict__ deg)
{
    int t = blockIdx.x * blockDim.x + threadIdx.x;
    int edge = t >> 5;
    if (edge >= N_EDGES) return;
    int lane = t & 31;
    int row = rows[edge]; int col = cols[edge]; float v = vals[edge];
    float4 xv = ((const float4*)(x + (size_t)col * D_FEAT))[lane];
    float* dst = agg + (size_t)row * D_FEAT + lane * 4;
    unsafeAtomicAdd(dst + 0, v * xv.x);
    unsafeAtomicAdd(dst + 1, v * xv.y);
    unsafeAtomicAdd(dst + 2, v * xv.z);
    unsafeAtomicAdd(dst + 3, v * xv.w);
    if (lane == 0) unsafeAtomicAdd(deg + row, v);
}

__global__ __launch_bounds__(256) void finalize_kernel(
    float* __restrict__ out, const float* __restrict__ deg,
    const float* __restrict__ bias)
{
    int t = blockIdx.x * blockDim.x + threadIdx.x;
    int node = t >> 5;
    if (node >= N_NODES) return;
    int lane = t & 31;
    float d = deg[node];
    float inv = (d == 0.f) ? 0.f : 1.f / d;
    float4* o = (float4*)(out + (size_t)node * D_FEAT) + lane;
    float4 bv = ((const float4*)bias)[lane];
    float4 ov = *o;
    ov.x = ov.x * inv + bv.x; ov.y = ov.y * inv + bv.y;
    ov.z = ov.z * inv + bv.z; ov.w = ov.w * inv + bv.w;
    *o = ov;
}

// ---------------- launch ----------------

extern "C" void kernel_launch(void* const* d_in, const int* in_sizes, int n_in,
                              void* d_out, int out_size, void* d_ws, size_t ws_size,
                              hipStream_t stream) {
    const float* x    = (const float*)d_in[0];
    const int*   rows = (const int*)  d_in[1];
    const int*   cols = (const int*)  d_in[2];
    const float* vals = (const float*)d_in[3];
    const float* bias = (const float*)d_in[4];
    float* out = (float*)d_out;

    // workspace layout (int offsets):
    //   counts    [0,      40000)
    //   offsets   [40064,  80065)   (40001 ints)
    //   cursors   [80128, 120128)
    //   blocksums [120128, 120448)
    //   bucket    [120448, 120448 + 1280000) as int2
    int* w = (int*)d_ws;
    int*  counts    = w;
    int*  offsets   = w + 40064;
    int*  cursors   = w + 80128;
    int*  blocksums = w + 120128;
    int2* bucket    = (int2*)(w + 120448);
    size_t needed = ((size_t)120448 + 2u * N_EDGES) * sizeof(int);

    if (ws_size >= needed) {
        hipMemsetAsync(counts, 0, N_NODES * sizeof(int), stream);
        histogram_kernel<<<(N_EDGES + 255) / 256, 256, 0, stream>>>(rows, counts);
        scan1_kernel<<<N_SCAN_BLOCKS, SCAN_BLOCK, 0, stream>>>(counts, offsets, blocksums);
        scan2_kernel<<<1, SCAN_BLOCK, 0, stream>>>(blocksums);
        scan3_kernel<<<N_SCAN_BLOCKS, SCAN_BLOCK, 0, stream>>>(offsets, cursors, blocksums);
        bucket_kernel<<<(N_EDGES + 255) / 256, 256, 0, stream>>>(rows, cols, vals, cursors, bucket);
        int threads = N_NODES * 32;
        gather_kernel<<<(threads + 255) / 256, 256, 0, stream>>>(x, offsets, bucket, bias, out);
    } else {
        float* deg = (float*)d_ws;
        hipMemsetAsync(out, 0, (size_t)N_NODES * D_FEAT * sizeof(float), stream);
        hipMemsetAsync(deg, 0, (size_t)N_NODES * sizeof(float), stream);
        int et = N_EDGES * 32;
        edge_scatter_kernel<<<(et + 255) / 256, 256, 0, stream>>>(x, rows, cols, vals, out, deg);
        int nt = N_NODES * 32;
        finalize_kernel<<<(nt + 255) / 256, 256, 0, stream>>>(out, deg, bias);
    }
}

// Round 4
// 159.637 us; speedup vs baseline: 7.4536x; 1.1628x over previous
//
#include <hip/hip_runtime.h>

#define N_NODES 40000
#define N_EDGES 640000
#define D_FEAT  128
#define CAP     32        // padded bucket slots per node (mean degree = 16)
#define OCAP    8192      // overflow list capacity (expected usage ~6 entries)
#define SCAN_BLOCK 256
#define N_SCAN_BLOCKS ((N_NODES + SCAN_BLOCK - 1) / SCAN_BLOCK)   // 157

// ================= Padded-bucket fast path =================

// One pass: slot from per-node cursor atomic; rare overflow to a side list.
__global__ __launch_bounds__(256) void scatter_kernel(
    const int*   __restrict__ rows,
    const int*   __restrict__ cols,
    const float* __restrict__ vals,
    int*         __restrict__ cursors,   // zeroed
    int2*        __restrict__ bucket,    // [N_NODES * CAP]
    int*         __restrict__ ocount,    // zeroed
    int4*        __restrict__ overflow)  // [OCAP]
{
    int e = blockIdx.x * blockDim.x + threadIdx.x;
    if (e >= N_EDGES) return;
    int   r = rows[e];
    int   c = cols[e];
    float v = vals[e];
    int slot = atomicAdd(&cursors[r], 1);
    if (slot < CAP) {
        bucket[(size_t)r * CAP + slot] = make_int2(c, __float_as_int(v));
    } else {
        int o = atomicAdd(ocount, 1);
        if (o < OCAP) overflow[o] = make_int4(r, c, __float_as_int(v), 0);
    }
}

// One half-wave (32 lanes) per node; unroll-4 for memory-level parallelism.
__global__ __launch_bounds__(256) void gather_pad_kernel(
    const float* __restrict__ x,
    const int*   __restrict__ cursors,
    const int2*  __restrict__ bucket,
    const int*   __restrict__ ocount,
    const int4*  __restrict__ overflow,
    const float* __restrict__ bias,
    float*       __restrict__ out)
{
    int t    = blockIdx.x * blockDim.x + threadIdx.x;
    int node = t >> 5;
    if (node >= N_NODES) return;
    int lane = t & 31;

    int cnt = cursors[node];
    int k   = min(cnt, CAP);
    const int2* base = bucket + (size_t)node * CAP;

    float4 acc0 = make_float4(0.f, 0.f, 0.f, 0.f);
    float4 acc1 = make_float4(0.f, 0.f, 0.f, 0.f);
    float  deg  = 0.f;

    int e = 0;
    for (; e + 4 <= k; e += 4) {
        int4 p0 = *(const int4*)(base + e);       // entries e, e+1
        int4 p1 = *(const int4*)(base + e + 2);   // entries e+2, e+3
        float v0 = __int_as_float(p0.y), v1 = __int_as_float(p0.w);
        float v2 = __int_as_float(p1.y), v3 = __int_as_float(p1.w);
        float4 x0 = ((const float4*)(x + (size_t)p0.x * D_FEAT))[lane];
        float4 x1 = ((const float4*)(x + (size_t)p0.z * D_FEAT))[lane];
        float4 x2 = ((const float4*)(x + (size_t)p1.x * D_FEAT))[lane];
        float4 x3 = ((const float4*)(x + (size_t)p1.z * D_FEAT))[lane];
        deg += (v0 + v1) + (v2 + v3);
        acc0.x += v0 * x0.x; acc0.y += v0 * x0.y; acc0.z += v0 * x0.z; acc0.w += v0 * x0.w;
        acc1.x += v1 * x1.x; acc1.y += v1 * x1.y; acc1.z += v1 * x1.z; acc1.w += v1 * x1.w;
        acc0.x += v2 * x2.x; acc0.y += v2 * x2.y; acc0.z += v2 * x2.z; acc0.w += v2 * x2.w;
        acc1.x += v3 * x3.x; acc1.y += v3 * x3.y; acc1.z += v3 * x3.z; acc1.w += v3 * x3.w;
    }
    for (; e < k; ++e) {
        int2 a = base[e];
        float v = __int_as_float(a.y);
        deg += v;
        float4 xv = ((const float4*)(x + (size_t)a.x * D_FEAT))[lane];
        acc0.x += v * xv.x; acc0.y += v * xv.y; acc0.z += v * xv.z; acc0.w += v * xv.w;
    }

    // Rare overflow entries (ocount==0 in the common case => loop skipped).
    int oc = min(*ocount, OCAP);
    for (int i = 0; i < oc; ++i) {
        int4 ent = overflow[i];
        if (ent.x == node) {
            float v = __int_as_float(ent.z);
            deg += v;
            float4 xv = ((const float4*)(x + (size_t)ent.y * D_FEAT))[lane];
            acc0.x += v * xv.x; acc0.y += v * xv.y; acc0.z += v * xv.z; acc0.w += v * xv.w;
        }
    }

    float inv = (deg == 0.f) ? 0.f : 1.f / deg;
    float4 bv = ((const float4*)bias)[lane];
    float4 ov;
    ov.x = (acc0.x + acc1.x) * inv + bv.x;
    ov.y = (acc0.y + acc1.y) * inv + bv.y;
    ov.z = (acc0.z + acc1.z) * inv + bv.z;
    ov.w = (acc0.w + acc1.w) * inv + bv.w;
    ((float4*)(out + (size_t)node * D_FEAT))[lane] = ov;
}

// ================= CSR middle path (round-3, general) =================

__global__ __launch_bounds__(256) void histogram_kernel(
    const int* __restrict__ rows, int* __restrict__ counts)
{
    int e = blockIdx.x * blockDim.x + threadIdx.x;
    if (e < N_EDGES) atomicAdd(&counts[rows[e]], 1);
}

__global__ __launch_bounds__(SCAN_BLOCK) void scan1_kernel(
    const int* __restrict__ counts, int* __restrict__ offsets, int* __restrict__ blocksums)
{
    __shared__ int tmp[SCAN_BLOCK];
    int t = threadIdx.x;
    int g = blockIdx.x * SCAN_BLOCK + t;
    int v = (g < N_NODES) ? counts[g] : 0;
    tmp[t] = v;
    __syncthreads();
    #pragma unroll
    for (int off = 1; off < SCAN_BLOCK; off <<= 1) {
        int add = (t >= off) ? tmp[t - off] : 0;
        __syncthreads();
        tmp[t] += add;
        __syncthreads();
    }
    if (g < N_NODES) offsets[g] = tmp[t] - v;
    if (t == SCAN_BLOCK - 1) blocksums[blockIdx.x] = tmp[t];
}

__global__ __launch_bounds__(SCAN_BLOCK) void scan2_kernel(int* __restrict__ blocksums)
{
    __shared__ int tmp[SCAN_BLOCK];
    int t = threadIdx.x;
    int v = (t < N_SCAN_BLOCKS) ? blocksums[t] : 0;
    tmp[t] = v;
    __syncthreads();
    #pragma unroll
    for (int off = 1; off < SCAN_BLOCK; off <<= 1) {
        int add = (t >= off) ? tmp[t - off] : 0;
        __syncthreads();
        tmp[t] += add;
        __syncthreads();
    }
    if (t < N_SCAN_BLOCKS) blocksums[t] = tmp[t] - v;
}

__global__ __launch_bounds__(SCAN_BLOCK) void scan3_kernel(
    int* __restrict__ offsets, int* __restrict__ cursors, const int* __restrict__ blocksums)
{
    int t = threadIdx.x;
    int g = blockIdx.x * SCAN_BLOCK + t;
    if (g < N_NODES) {
        int o = offsets[g] + blocksums[blockIdx.x];
        offsets[g] = o;
        cursors[g] = o;
    }
    if (g == 0) offsets[N_NODES] = N_EDGES;
}

__global__ __launch_bounds__(256) void bucket_kernel(
    const int* __restrict__ rows, const int* __restrict__ cols,
    const float* __restrict__ vals, int* __restrict__ cursors, int2* __restrict__ bucket)
{
    int e = blockIdx.x * blockDim.x + threadIdx.x;
    if (e >= N_EDGES) return;
    int r = rows[e];
    int pos = atomicAdd(&cursors[r], 1);
    bucket[pos] = make_int2(cols[e], __float_as_int(vals[e]));
}

__global__ __launch_bounds__(256) void gather_csr_kernel(
    const float* __restrict__ x, const int* __restrict__ offsets,
    const int2* __restrict__ bucket, const float* __restrict__ bias,
    float* __restrict__ out)
{
    int t = blockIdx.x * blockDim.x + threadIdx.x;
    int node = t >> 5;
    if (node >= N_NODES) return;
    int lane = t & 31;
    int beg = offsets[node];
    int end = offsets[node + 1];
    float4 acc = make_float4(0.f, 0.f, 0.f, 0.f);
    float deg = 0.f;
    int2 ent = (beg < end) ? bucket[beg] : make_int2(0, 0);
    for (int e = beg; e < end; ++e) {
        int2 cur = ent;
        if (e + 1 < end) ent = bucket[e + 1];
        float v = __int_as_float(cur.y);
        deg += v;
        float4 xv = ((const float4*)(x + (size_t)cur.x * D_FEAT))[lane];
        acc.x += v * xv.x; acc.y += v * xv.y; acc.z += v * xv.z; acc.w += v * xv.w;
    }
    float inv = (deg == 0.f) ? 0.f : 1.f / deg;
    float4 bv = ((const float4*)bias)[lane];
    float4 ov;
    ov.x = acc.x * inv + bv.x; ov.y = acc.y * inv + bv.y;
    ov.z = acc.z * inv + bv.z; ov.w = acc.w * inv + bv.w;
    ((float4*)(out + (size_t)node * D_FEAT))[lane] = ov;
}

// ================= Atomic fallback =================

__global__ __launch_bounds__(256) void edge_scatter_kernel(
    const float* __restrict__ x, const int* __restrict__ rows,
    const int* __restrict__ cols, const float* __restrict__ vals,
    float* __restrict__ agg, float* __restrict__ deg)
{
    int t = blockIdx.x * blockDim.x + threadIdx.x;
    int edge = t >> 5;
    if (edge >= N_EDGES) return;
    int lane = t & 31;
    int row = rows[edge]; int col = cols[edge]; float v = vals[edge];
    float4 xv = ((const float4*)(x + (size_t)col * D_FEAT))[lane];
    float* dst = agg + (size_t)row * D_FEAT + lane * 4;
    unsafeAtomicAdd(dst + 0, v * xv.x);
    unsafeAtomicAdd(dst + 1, v * xv.y);
    unsafeAtomicAdd(dst + 2, v * xv.z);
    unsafeAtomicAdd(dst + 3, v * xv.w);
    if (lane == 0) unsafeAtomicAdd(deg + row, v);
}

__global__ __launch_bounds__(256) void finalize_kernel(
    float* __restrict__ out, const float* __restrict__ deg, const float* __restrict__ bias)
{
    int t = blockIdx.x * blockDim.x + threadIdx.x;
    int node = t >> 5;
    if (node >= N_NODES) return;
    int lane = t & 31;
    float d = deg[node];
    float inv = (d == 0.f) ? 0.f : 1.f / d;
    float4* o = (float4*)(out + (size_t)node * D_FEAT) + lane;
    float4 bv = ((const float4*)bias)[lane];
    float4 ov = *o;
    ov.x = ov.x * inv + bv.x; ov.y = ov.y * inv + bv.y;
    ov.z = ov.z * inv + bv.z; ov.w = ov.w * inv + bv.w;
    *o = ov;
}

// ================= launch =================

extern "C" void kernel_launch(void* const* d_in, const int* in_sizes, int n_in,
                              void* d_out, int out_size, void* d_ws, size_t ws_size,
                              hipStream_t stream) {
    const float* x    = (const float*)d_in[0];
    const int*   rows = (const int*)  d_in[1];
    const int*   cols = (const int*)  d_in[2];
    const float* vals = (const float*)d_in[3];
    const float* bias = (const float*)d_in[4];
    float* out = (float*)d_out;

    // Padded-path layout (bytes):
    //   cursors [0, 160000) | ocount [160000,160004) | pad | overflow @160016 (OCAP*16)
    //   bucket @ 291328 (N_NODES*CAP*8)
    char* wb = (char*)d_ws;
    int*  p_cursors  = (int*) wb;
    int*  p_ocount   = (int*) (wb + 160000);
    int4* p_overflow = (int4*)(wb + 160016);
    int2* p_bucket   = (int2*)(wb + 291328);
    size_t need_pad = 291328 + (size_t)N_NODES * CAP * sizeof(int2);   // ~10.5 MB

    // CSR-path layout (ints): counts | offsets@40064 | cursors@80128 | blocksums@120128 | bucket@120448
    int* w = (int*)d_ws;
    size_t need_csr = ((size_t)120448 + 2u * N_EDGES) * sizeof(int);   // ~5.6 MB

    if (ws_size >= need_pad) {
        hipMemsetAsync(p_cursors, 0, 160004, stream);  // cursors + ocount
        scatter_kernel<<<(N_EDGES + 255) / 256, 256, 0, stream>>>(
            rows, cols, vals, p_cursors, p_bucket, p_ocount, p_overflow);
        int threads = N_NODES * 32;
        gather_pad_kernel<<<(threads + 255) / 256, 256, 0, stream>>>(
            x, p_cursors, p_bucket, p_ocount, p_overflow, bias, out);
    } else if (ws_size >= need_csr) {
        int*  counts    = w;
        int*  offsets   = w + 40064;
        int*  cursors   = w + 80128;
        int*  blocksums = w + 120128;
        int2* bucket    = (int2*)(w + 120448);
        hipMemsetAsync(counts, 0, N_NODES * sizeof(int), stream);
        histogram_kernel<<<(N_EDGES + 255) / 256, 256, 0, stream>>>(rows, counts);
        scan1_kernel<<<N_SCAN_BLOCKS, SCAN_BLOCK, 0, stream>>>(counts, offsets, blocksums);
        scan2_kernel<<<1, SCAN_BLOCK, 0, stream>>>(blocksums);
        scan3_kernel<<<N_SCAN_BLOCKS, SCAN_BLOCK, 0, stream>>>(offsets, cursors, blocksums);
        bucket_kernel<<<(N_EDGES + 255) / 256, 256, 0, stream>>>(rows, cols, vals, cursors, bucket);
        int threads = N_NODES * 32;
        gather_csr_kernel<<<(threads + 255) / 256, 256, 0, stream>>>(x, offsets, bucket, bias, out);
    } else {
        float* deg = (float*)d_ws;
        hipMemsetAsync(out, 0, (size_t)N_NODES * D_FEAT * sizeof(float), stream);
        hipMemsetAsync(deg, 0, (size_t)N_NODES * sizeof(float), stream);
        int et = N_EDGES * 32;
        edge_scatter_kernel<<<(et + 255) / 256, 256, 0, stream>>>(x, rows, cols, vals, out, deg);
        int nt = N_NODES * 32;
        finalize_kernel<<<(nt + 255) / 256, 256, 0, stream>>>(out, deg, bias);
    }
}